// Round 1
// 73.531 us; speedup vs baseline: 1.0016x; 1.0016x over previous
//
#include <hip/hip_runtime.h>

#define BM 64
#define BN 64
#define BK 64
#define VIG 0.75f

// Kernel 1: split-K fuzzy-AND accumulation (min-plus GEMM).
// Grid: (N/BM, C/BN, ksplit). Block: 256 threads, each computes a 4x4 output tile.
// BK=64 so the common ksplit=4 path (kchunk=64) is a single stage->sync->compute
// pass: 2 barriers per block instead of 4.
// LDS tiles stored [K][M] with XOR swizzle on the 4-float granule index:
//   element (k, m) lives at k*64 + (((m>>2) ^ ((k>>2)&3))<<2 | (m&3)).
// Staging stores land <=2-way bank conflicts (free), fragment b128 reads conflict-free.
__global__ __launch_bounds__(256) void fuzzy_scores_kernel(
    const float* __restrict__ x, const float* __restrict__ w,
    float* __restrict__ out0, float* __restrict__ wsbuf,
    int N, int C, int D, int kchunk)
{
    __shared__ float sA[BK * BM];   // 16 KB
    __shared__ float sB[BK * BN];   // 16 KB

    const int t  = threadIdx.x;
    const int cx = t & 15;   // column group (coalesced epilogue stores)
    const int ry = t >> 4;   // row group
    const int bx = blockIdx.x, by = blockIdx.y, bz = blockIdx.z;
    const int d0 = bz * kchunk;

    float acc[4][4];
#pragma unroll
    for (int i = 0; i < 4; ++i)
#pragma unroll
        for (int j = 0; j < 4; ++j) acc[i][j] = 0.f;

    for (int kb = 0; kb < kchunk; kb += BK) {
        __syncthreads();  // protect LDS from previous iteration's readers (no-op 1st iter)
#pragma unroll
        for (int l = 0; l < 4; ++l) {
            const int q  = l * 256 + t;       // 0..1023
            const int rr = q >> 4;            // row within tile, 0..63
            const int kq = (q & 15) << 2;     // k offset, multiple of 4, 0..60
            const int c3 = q & 3;             // == (k>>2)&3 for k in [kq, kq+3]
            const int gb = ((((rr >> 2) ^ c3) << 2) | (rr & 3));

            const float4 v = *(const float4*)(x + (size_t)(bx * BM + rr) * D + d0 + kb + kq);
            sA[(kq + 0) * BM + gb] = v.x;
            sA[(kq + 1) * BM + gb] = v.y;
            sA[(kq + 2) * BM + gb] = v.z;
            sA[(kq + 3) * BM + gb] = v.w;

            const float4 u = *(const float4*)(w + (size_t)(by * BN + rr) * D + d0 + kb + kq);
            sB[(kq + 0) * BN + gb] = u.x;
            sB[(kq + 1) * BN + gb] = u.y;
            sB[(kq + 2) * BN + gb] = u.z;
            sB[(kq + 3) * BN + gb] = u.w;
        }
        __syncthreads();

#pragma unroll 16
        for (int k = 0; k < BK; ++k) {
            const int c3 = (k >> 2) & 3;
            const float4 a = *(const float4*)&sA[k * BM + ((ry ^ c3) << 2)];
            const float4 b = *(const float4*)&sB[k * BN + ((cx ^ c3) << 2)];
            const float av[4] = {a.x, a.y, a.z, a.w};
            const float bv[4] = {b.x, b.y, b.z, b.w};
#pragma unroll
            for (int i = 0; i < 4; ++i)
#pragma unroll
                for (int j = 0; j < 4; ++j)
                    acc[i][j] += fminf(av[i], bv[j]);
        }
    }

    float* dst = (bz == 0) ? out0 : (wsbuf + (size_t)(bz - 1) * N * C);
    const int col = by * BN + (cx << 2);
#pragma unroll
    for (int i = 0; i < 4; ++i) {
        const int row = bx * BM + (ry << 2) + i;
        *(float4*)(dst + (size_t)row * C + col) =
            make_float4(acc[i][0], acc[i][1], acc[i][2], acc[i][3]);
    }
}

// Kernel 2: per-row finish, vectorized. 2 rows per block, 128 threads per row,
// float4 partial loads. Sums split-K partials in order (out0, p=1..ksplit-1) ->
// identical FP summation order to the reference's sequential d-scan, divides by
// row-sum of x, vigilance-gates, writes final scores, computes argmax (strict >
// with explicit min-index tie-break -> first index wins; all-zero row -> 0).
// Grid: N/2 blocks of 256 threads (D == 256, C == 512 assumed).
__global__ __launch_bounds__(256) void fuzzy_finish_kernel(
    const float* __restrict__ x, float* __restrict__ out,
    const float* __restrict__ wsbuf, int N, int C, int D, int ksplit)
{
    const int t    = threadIdx.x;
    const int r    = t >> 7;          // row within block: 0/1
    const int u    = t & 127;         // 128 threads per row
    const int n    = blockIdx.x * 2 + r;
    const int lane = t & 63;
    const int wid  = t >> 6;          // 0..3 (waves 0,1 -> row 0; waves 2,3 -> row 1)

    // row sum of x: 128 threads x float2 (D == 256)
    const float2 xv = *(const float2*)(x + (size_t)n * D + 2 * u);
    float v = xv.x + xv.y;
#pragma unroll
    for (int s = 1; s < 64; s <<= 1) v += __shfl_xor(v, s);
    __shared__ float wsum[4];
    if (lane == 0) wsum[wid] = v;
    __syncthreads();
    const float sumx = wsum[2 * r] + wsum[2 * r + 1];

    // this thread's 4 columns: 4u .. 4u+3  (128 threads x 4 = C = 512)
    const int    c0  = 4 * u;
    const size_t off = (size_t)n * C + c0;
    float4 acc = *(const float4*)(out + off);
    for (int p = 1; p < ksplit; ++p) {
        const float4 w4 = *(const float4*)(wsbuf + (size_t)(p - 1) * N * C + off);
        acc.x += w4.x; acc.y += w4.y; acc.z += w4.z; acc.w += w4.w;
    }
    float4 m;
    m.x = acc.x / sumx;
    m.y = acc.y / sumx;
    m.z = acc.z / sumx;
    m.w = acc.w / sumx;
    m.x = (m.x >= VIG) ? m.x : 0.f;
    m.y = (m.y >= VIG) ? m.y : 0.f;
    m.z = (m.z >= VIG) ? m.z : 0.f;
    m.w = (m.w >= VIG) ? m.w : 0.f;
    *(float4*)(out + off) = m;

    // per-thread argmax over its 4 ascending columns (strict > -> first wins)
    float best = -1.f;
    int   bidx = 0;
    if (m.x > best) { best = m.x; bidx = c0 + 0; }
    if (m.y > best) { best = m.y; bidx = c0 + 1; }
    if (m.z > best) { best = m.z; bidx = c0 + 2; }
    if (m.w > best) { best = m.w; bidx = c0 + 3; }

    // wave argmax reduce (lexicographic max on (value, -index))
#pragma unroll
    for (int s2 = 1; s2 < 64; s2 <<= 1) {
        const float ov = __shfl_xor(best, s2);
        const int   oi = __shfl_xor(bidx, s2);
        if (ov > best || (ov == best && oi < bidx)) { best = ov; bidx = oi; }
    }
    __shared__ float bvs[4];
    __shared__ int   bis[4];
    if (lane == 0) { bvs[wid] = best; bis[wid] = bidx; }
    __syncthreads();
    if (u == 0) {  // one thread per row (t = 0 and t = 128)
        float fb = bvs[2 * r];
        int   fi = bis[2 * r];
        if (bvs[2 * r + 1] > fb || (bvs[2 * r + 1] == fb && bis[2 * r + 1] < fi)) {
            fb = bvs[2 * r + 1];
            fi = bis[2 * r + 1];
        }
        out[(size_t)N * C + n] = (float)fi;
    }
}

extern "C" void kernel_launch(void* const* d_in, const int* in_sizes, int n_in,
                              void* d_out, int out_size, void* d_ws, size_t ws_size,
                              hipStream_t stream) {
    const float* x = (const float*)d_in[0];
    const float* w = (const float*)d_in[1];
    float* out = (float*)d_out;
    float* ws  = (float*)d_ws;

    const int D = 256;
    const int N = in_sizes[0] / D;   // 1024
    const int C = in_sizes[1] / D;   // 512

    const size_t partial_bytes = (size_t)N * C * sizeof(float);  // 2 MB
    int ksplit = 1;
    if (ws_size >= 3 * partial_bytes)      ksplit = 4;
    else if (ws_size >= partial_bytes)     ksplit = 2;
    const int kchunk = D / ksplit;

    dim3 grid(N / BM, C / BN, ksplit);
    fuzzy_scores_kernel<<<grid, 256, 0, stream>>>(x, w, out, ws, N, C, D, kchunk);
    fuzzy_finish_kernel<<<N / 2, 256, 0, stream>>>(x, out, ws, N, C, D, ksplit);
}